// Round 2
// baseline (65.638 us; speedup 1.0000x reference)
//
#include <hip/hip_runtime.h>
#include <math.h>

#define NBANDS 5
#define PFUNC_ELEMS (32*128*64*64)
#define LOG2E 1.4426950408889634f

__global__ __launch_bounds__(256) void bfp_kernel(
        const float* __restrict__ x,      // (32,5,64,128)
        const float* __restrict__ adj,    // (64,64)
        const float* __restrict__ amask,  // (32,128,5)
        const float* __restrict__ alpha,  // (32,128,5)
        const float* __restrict__ We,     // (5,64)
        const float* __restrict__ be,     // (5,64)
        const float* __restrict__ Wq,     // (16,64)
        const float* __restrict__ Wk,     // (16,64)
        float* __restrict__ out) {
    // XCD-bijective swizzle: 4096 blocks / 8 XCDs -> contiguous bt per XCD
    const int bid = blockIdx.x;
    const int bt = (bid & 7) * 512 + (bid >> 3);
    const int b = bt >> 7;
    const int t = bt & 127;
    const int tid = threadIdx.x;

    __shared__ __align__(16) float x_s[NBANDS][64];
    __shared__ float acw_s[NBANDS], bcw_s[NBANDS];
    __shared__ float xmax_s[NBANDS], xmin_s[NBANDS], xbar_s[NBANDS];
    __shared__ float w_s[NBANDS], mask_s[NBANDS];

    const int i = tid >> 2;          // output row
    const int j0 = (tid & 3) << 4;   // first of 16 owned columns

    // adjacency row chunk (coalesced float4s) -> 0/1 mask registers
    const float4 a0 = *(const float4*)(adj + i * 64 + j0);
    const float4 a1 = *(const float4*)(adj + i * 64 + j0 + 4);
    const float4 a2 = *(const float4*)(adj + i * 64 + j0 + 8);
    const float4 a3 = *(const float4*)(adj + i * 64 + j0 + 12);

    // stage x_t[b,t,n,c] = x[b,n,c,t]
    for (int idx = tid; idx < NBANDS * 64; idx += 256)
        x_s[idx >> 6][idx & 63] = x[((size_t)b * 320 + idx) * 128 + t];

    if (tid < NBANDS) {
        float mk = amask[((size_t)b * 128 + t) * NBANDS + tid];
        mask_s[tid] = mk;
        w_s[tid] = alpha[((size_t)b * 128 + t) * NBANDS + tid] * mk;
    }

    // band scalars AC,BC (threads 64..143: n = band, s = d_s index)
    if (tid >= 64 && tid < 64 + NBANDS * 16) {
        int k = tid - 64, n = k >> 4, s = k & 15;
        float u = 0.f, v = 0.f, w = 0.f;
        for (int d = 0; d < 64; ++d) {
            float we = We[n * 64 + d], bb = be[n * 64 + d];
            float wq = Wq[s * 64 + d], wk = Wk[s * 64 + d];
            u = fmaf(wq, we, u);   // A_s
            v = fmaf(wk, we, v);   // C_s
            w = fmaf(wq, bb, w);   // B_s
        }
        float ac = u * v, bc = w * v;
        #pragma unroll
        for (int mk = 8; mk >= 1; mk >>= 1) {
            ac += __shfl_xor(ac, mk);
            bc += __shfl_xor(bc, mk);
        }
        if (s == 0) {
            acw_s[n] = 0.25f * LOG2E * ac;   // log2e folded in: raw v_exp_f32 later
            bcw_s[n] = 0.25f * LOG2E * bc;
        }
    }
    __syncthreads();

    // per-band sum/min/max of x (wave w handles band w; wave 0 also band 4)
    {
        const int lane = tid & 63;
        for (int n = tid >> 6; n < NBANDS; n += 4) {
            float v = x_s[n][lane];
            float sm = v, mx = v, mn = v;
            #pragma unroll
            for (int mk = 32; mk >= 1; mk >>= 1) {
                sm += __shfl_xor(sm, mk);
                mx = fmaxf(mx, __shfl_xor(mx, mk));
                mn = fminf(mn, __shfl_xor(mn, mk));
            }
            if (lane == 0) {
                xbar_s[n] = sm * (1.f / 64.f);
                xmax_s[n] = mx;
                xmin_s[n] = mn;
            }
        }
    }
    __syncthreads();

    // embeddings_mean[b,t,:]
    if (tid < 64) {
        float cnt = 0.f, accm = 0.f;
        #pragma unroll
        for (int n = 0; n < NBANDS; ++n) {
            cnt += mask_s[n];
            accm += mask_s[n] * fmaf(xbar_s[n], We[n * 64 + tid], be[n * 64 + tid]);
        }
        out[PFUNC_ELEMS + (size_t)bt * 64 + tid] = accm / fmaxf(cnt, 1.f);
    }

    float maskf[16];
    maskf[0]  = a0.x > 0.f ? 1.f : 0.f;  maskf[1]  = a0.y > 0.f ? 1.f : 0.f;
    maskf[2]  = a0.z > 0.f ? 1.f : 0.f;  maskf[3]  = a0.w > 0.f ? 1.f : 0.f;
    maskf[4]  = a1.x > 0.f ? 1.f : 0.f;  maskf[5]  = a1.y > 0.f ? 1.f : 0.f;
    maskf[6]  = a1.z > 0.f ? 1.f : 0.f;  maskf[7]  = a1.w > 0.f ? 1.f : 0.f;
    maskf[8]  = a2.x > 0.f ? 1.f : 0.f;  maskf[9]  = a2.y > 0.f ? 1.f : 0.f;
    maskf[10] = a2.z > 0.f ? 1.f : 0.f;  maskf[11] = a2.w > 0.f ? 1.f : 0.f;
    maskf[12] = a3.x > 0.f ? 1.f : 0.f;  maskf[13] = a3.y > 0.f ? 1.f : 0.f;
    maskf[14] = a3.z > 0.f ? 1.f : 0.f;  maskf[15] = a3.w > 0.f ? 1.f : 0.f;

    float acc[16];
    #pragma unroll
    for (int jj = 0; jj < 16; ++jj) acc[jj] = 0.f;

    for (int n = 0; n < NBANDS; ++n) {
        // logits coefficient with log2e pre-folded: s_j = g2 * x_j  (base-2)
        const float g2 = fmaf(acw_s[n], x_s[n][i], bcw_s[n]);
        // conservative row bound (>= all s_j): exp2 in (0,1], provably no Z underflow
        const float m = (g2 >= 0.f) ? g2 * xmax_s[n] : g2 * xmin_s[n];
        const float4* xp = (const float4*)(&x_s[n][j0]);
        float p[16];
        float Z = 0.f;
        #pragma unroll
        for (int q = 0; q < 4; ++q) {
            float4 xv = xp[q];
            float e0 = __builtin_amdgcn_exp2f(fmaf(g2, xv.x, -m)) * maskf[4 * q + 0];
            float e1 = __builtin_amdgcn_exp2f(fmaf(g2, xv.y, -m)) * maskf[4 * q + 1];
            float e2 = __builtin_amdgcn_exp2f(fmaf(g2, xv.z, -m)) * maskf[4 * q + 2];
            float e3 = __builtin_amdgcn_exp2f(fmaf(g2, xv.w, -m)) * maskf[4 * q + 3];
            p[4 * q + 0] = e0; p[4 * q + 1] = e1;
            p[4 * q + 2] = e2; p[4 * q + 3] = e3;
            Z += (e0 + e1) + (e2 + e3);
        }
        Z += __shfl_xor(Z, 1);
        Z += __shfl_xor(Z, 2);
        const float sc = w_s[n] * __builtin_amdgcn_rcpf(Z);  // Z>0 (self-loop)
        #pragma unroll
        for (int jj = 0; jj < 16; ++jj) acc[jj] = fmaf(p[jj], sc, acc[jj]);
    }

    float4* outp = (float4*)(out + ((size_t)bt * 64 + i) * 64 + j0);
    #pragma unroll
    for (int q = 0; q < 4; ++q)
        outp[q] = make_float4(acc[4 * q], acc[4 * q + 1], acc[4 * q + 2], acc[4 * q + 3]);
}

extern "C" void kernel_launch(void* const* d_in, const int* in_sizes, int n_in,
                              void* d_out, int out_size, void* d_ws, size_t ws_size,
                              hipStream_t stream) {
    const float* x     = (const float*)d_in[0];
    const float* adj   = (const float*)d_in[1];
    const float* amask = (const float*)d_in[2];
    const float* alpha = (const float*)d_in[3];
    const float* We    = (const float*)d_in[4];
    const float* be    = (const float*)d_in[5];
    const float* Wq    = (const float*)d_in[6];
    const float* Wk    = (const float*)d_in[7];
    float* out = (float*)d_out;

    bfp_kernel<<<4096, 256, 0, stream>>>(x, adj, amask, alpha, We, be, Wq, Wk, out);
}

// Round 3
// 36.258 us; speedup vs baseline: 1.8103x; 1.8103x over previous
//
#include <hip/hip_runtime.h>
#include <math.h>

#define NBANDS 5
#define PFUNC_ELEMS (32*128*64*64)
#define LOG2E 1.4426950408889634f

// ws layout (floats): [0,5) acw  (0.25*log2e*AC per band)
//                     [8,13) bcw (0.25*log2e*BC per band)

__global__ void bfp_prep_kernel(const float* __restrict__ We,
                                const float* __restrict__ be,
                                const float* __restrict__ Wq,
                                const float* __restrict__ Wk,
                                float* __restrict__ ws) {
    int tid = threadIdx.x;              // 80 threads: n = tid>>4, s = tid&15
    if (tid < NBANDS * 16) {
        int n = tid >> 4, s = tid & 15;
        float u = 0.f, v = 0.f, w = 0.f;
        for (int d = 0; d < 64; ++d) {
            float we = We[n * 64 + d], bb = be[n * 64 + d];
            float wq = Wq[s * 64 + d], wk = Wk[s * 64 + d];
            u = fmaf(wq, we, u);   // A_s
            v = fmaf(wk, we, v);   // C_s
            w = fmaf(wq, bb, w);   // B_s
        }
        float ac = u * v, bc = w * v;
        #pragma unroll
        for (int mk = 8; mk >= 1; mk >>= 1) {
            ac += __shfl_xor(ac, mk);
            bc += __shfl_xor(bc, mk);
        }
        if (s == 0) {
            ws[n]     = 0.25f * LOG2E * ac;
            ws[8 + n] = 0.25f * LOG2E * bc;
        }
    }
}

__global__ __launch_bounds__(512) void bfp_main_kernel(
        const float* __restrict__ x,      // (32,5,64,128)
        const float* __restrict__ adj,    // (64,64) values in {0,1}
        const float* __restrict__ amask,  // (32,128,5)
        const float* __restrict__ alpha,  // (32,128,5)
        const float* __restrict__ We,     // (5,64)
        const float* __restrict__ be,     // (5,64)
        const float* __restrict__ ws,
        float* __restrict__ out) {
    // XCD-bijective swizzle: 4096 % 8 == 0 -> contiguous bt chunk per XCD
    const int bid = blockIdx.x;
    const int bt = (bid & 7) * 512 + (bid >> 3);
    const int b = bt >> 7;
    const int t = bt & 127;
    const int tid = threadIdx.x;

    __shared__ __align__(16) float x_s[NBANDS][64];
    __shared__ float xmax_s[NBANDS], xmin_s[NBANDS], xbar_s[NBANDS];
    __shared__ float w_s[NBANDS], mask_s[NBANDS];

    const int i = tid >> 3;          // output row 0..63
    const int j0 = (tid & 7) << 3;   // first of 8 owned columns

    // adjacency chunk: raw 0/1 floats, used directly as multiplicative mask
    const float4 a0 = *(const float4*)(adj + i * 64 + j0);
    const float4 a1 = *(const float4*)(adj + i * 64 + j0 + 4);

    // stage x_t[b,t,n,c] = x[b,n,c,t]
    if (tid < NBANDS * 64)
        x_s[tid >> 6][tid & 63] = x[((size_t)b * 320 + tid) * 128 + t];
    if (tid < NBANDS) {
        float mk = amask[((size_t)b * 128 + t) * NBANDS + tid];
        mask_s[tid] = mk;
        w_s[tid] = alpha[((size_t)b * 128 + t) * NBANDS + tid] * mk;
    }
    __syncthreads();

    // per-band sum/min/max of x: wave n handles band n (waves 0..4)
    {
        const int wv = tid >> 6, lane = tid & 63;
        if (wv < NBANDS) {
            float v = x_s[wv][lane];
            float sm = v, mx = v, mn = v;
            #pragma unroll
            for (int mk = 32; mk >= 1; mk >>= 1) {
                sm += __shfl_xor(sm, mk);
                mx = fmaxf(mx, __shfl_xor(mx, mk));
                mn = fminf(mn, __shfl_xor(mn, mk));
            }
            if (lane == 0) {
                xbar_s[wv] = sm * (1.f / 64.f);
                xmax_s[wv] = mx;
                xmin_s[wv] = mn;
            }
        }
    }
    __syncthreads();

    // embeddings_mean[b,t,:]
    if (tid < 64) {
        float cnt = 0.f, accm = 0.f;
        #pragma unroll
        for (int n = 0; n < NBANDS; ++n) {
            cnt += mask_s[n];
            accm += mask_s[n] * fmaf(xbar_s[n], We[n * 64 + tid], be[n * 64 + tid]);
        }
        out[PFUNC_ELEMS + (size_t)bt * 64 + tid] = accm / fmaxf(cnt, 1.f);
    }

    float maskf[8] = {a0.x, a0.y, a0.z, a0.w, a1.x, a1.y, a1.z, a1.w};

    float acc[8];
    #pragma unroll
    for (int jj = 0; jj < 8; ++jj) acc[jj] = 0.f;

    #pragma unroll
    for (int n = 0; n < NBANDS; ++n) {
        // base-2 logits coefficient (0.25*log2e pre-folded into acw/bcw)
        const float g2 = fmaf(ws[n], x_s[n][i], ws[8 + n]);
        // conservative row bound >= all logits -> exp2 args <= 0
        const float m = (g2 >= 0.f) ? g2 * xmax_s[n] : g2 * xmin_s[n];
        const float4 xv0 = ((const float4*)(&x_s[n][j0]))[0];
        const float4 xv1 = ((const float4*)(&x_s[n][j0]))[1];
        float p[8];
        p[0] = __builtin_amdgcn_exp2f(fmaf(g2, xv0.x, -m)) * maskf[0];
        p[1] = __builtin_amdgcn_exp2f(fmaf(g2, xv0.y, -m)) * maskf[1];
        p[2] = __builtin_amdgcn_exp2f(fmaf(g2, xv0.z, -m)) * maskf[2];
        p[3] = __builtin_amdgcn_exp2f(fmaf(g2, xv0.w, -m)) * maskf[3];
        p[4] = __builtin_amdgcn_exp2f(fmaf(g2, xv1.x, -m)) * maskf[4];
        p[5] = __builtin_amdgcn_exp2f(fmaf(g2, xv1.y, -m)) * maskf[5];
        p[6] = __builtin_amdgcn_exp2f(fmaf(g2, xv1.z, -m)) * maskf[6];
        p[7] = __builtin_amdgcn_exp2f(fmaf(g2, xv1.w, -m)) * maskf[7];
        float Z = ((p[0] + p[1]) + (p[2] + p[3])) + ((p[4] + p[5]) + (p[6] + p[7]));
        Z += __shfl_xor(Z, 1);
        Z += __shfl_xor(Z, 2);
        Z += __shfl_xor(Z, 4);
        const float sc = w_s[n] * __builtin_amdgcn_rcpf(fmaxf(Z, 1e-30f));
        #pragma unroll
        for (int jj = 0; jj < 8; ++jj) acc[jj] = fmaf(p[jj], sc, acc[jj]);
    }

    float4* outp = (float4*)(out + ((size_t)bt * 64 + i) * 64 + j0);
    outp[0] = make_float4(acc[0], acc[1], acc[2], acc[3]);
    outp[1] = make_float4(acc[4], acc[5], acc[6], acc[7]);
}

extern "C" void kernel_launch(void* const* d_in, const int* in_sizes, int n_in,
                              void* d_out, int out_size, void* d_ws, size_t ws_size,
                              hipStream_t stream) {
    const float* x     = (const float*)d_in[0];
    const float* adj   = (const float*)d_in[1];
    const float* amask = (const float*)d_in[2];
    const float* alpha = (const float*)d_in[3];
    const float* We    = (const float*)d_in[4];
    const float* be    = (const float*)d_in[5];
    const float* Wq    = (const float*)d_in[6];
    const float* Wk    = (const float*)d_in[7];
    float* ws  = (float*)d_ws;
    float* out = (float*)d_out;

    bfp_prep_kernel<<<1, 80, 0, stream>>>(We, be, Wq, Wk, ws);
    bfp_main_kernel<<<4096, 512, 0, stream>>>(x, adj, amask, alpha, We, be, ws, out);
}

// Round 5
// 34.318 us; speedup vs baseline: 1.9126x; 1.0565x over previous
//
#include <hip/hip_runtime.h>
#include <math.h>

#define NBANDS 5
#define T_TILE 4
#define PFUNC_ELEMS (32*128*64*64)
#define LOG2E 1.4426950408889634f

// ws layout (floats): [0,5) acw = 0.25*log2e*AC[n] ; [8,13) bcw = 0.25*log2e*BC[n]

__global__ void bfp_prep_kernel(const float* __restrict__ We,
                                const float* __restrict__ be,
                                const float* __restrict__ Wq,
                                const float* __restrict__ Wk,
                                float* __restrict__ ws) {
    // 320 threads: wave n = tid>>6 handles band n; lane: s = lane>>2, d-chunk q = lane&3
    const int n = threadIdx.x >> 6;
    const int lane = threadIdx.x & 63;
    const int s = lane >> 2;
    const int d0 = (lane & 3) * 16;
    if (n >= NBANDS) return;

    float u = 0.f, v = 0.f, w = 0.f;
    #pragma unroll
    for (int dd = 0; dd < 16; ++dd) {
        int d = d0 + dd;
        float we = We[n * 64 + d], bb = be[n * 64 + d];
        float wq = Wq[s * 64 + d], wk = Wk[s * 64 + d];
        u = fmaf(wq, we, u);   // A_s partial
        v = fmaf(wk, we, v);   // C_s partial
        w = fmaf(wq, bb, w);   // B_s partial
    }
    // complete each s over its 4 d-chunks (quad xor on bits 0-1)
    #pragma unroll
    for (int mk = 1; mk <= 2; mk <<= 1) {
        u += __shfl_xor(u, mk);
        v += __shfl_xor(v, mk);
        w += __shfl_xor(w, mk);
    }
    float ac = u * v, bc = w * v;   // per-s products (all 4 lanes of a quad identical)
    // sum over s: xor on bits 2-5 keeps lane&3 fixed -> orbit hits each s EXACTLY ONCE
    #pragma unroll
    for (int mk = 4; mk <= 32; mk <<= 1) {
        ac += __shfl_xor(ac, mk);
        bc += __shfl_xor(bc, mk);
    }
    if (lane == 0) {
        ws[n]     = 0.25f * LOG2E * ac;   // 0.25 = 1/sqrt(d_s) only; no dedup factor
        ws[8 + n] = 0.25f * LOG2E * bc;
    }
}

__global__ __launch_bounds__(512) void bfp_main_kernel(
        const float* __restrict__ x,      // (32,5,64,128)
        const float* __restrict__ adj,    // (64,64), values in {0,1}
        const float* __restrict__ amask,  // (32,128,5)
        const float* __restrict__ alpha,  // (32,128,5)
        const float* __restrict__ We,     // (5,64)
        const float* __restrict__ be,     // (5,64)
        const float* __restrict__ ws,
        float* __restrict__ out) {
    // 1024 blocks; XCD-bijective swizzle (1024 % 8 == 0): contiguous chunk per XCD
    const int bid = blockIdx.x;
    const int blk = (bid & 7) * 128 + (bid >> 3);
    const int bt0 = blk * T_TILE;         // first of 4 consecutive bt
    const int b = bt0 >> 7;
    const int t0 = bt0 & 127;             // multiple of 4
    const int tid = threadIdx.x;

    __shared__ __align__(16) float x_s[T_TILE][NBANDS][64];
    __shared__ float xbar_s[T_TILE][NBANDS], xmax_s[T_TILE][NBANDS], xmin_s[T_TILE][NBANDS];
    __shared__ float w_s[T_TILE][NBANDS], mask_s[T_TILE][NBANDS];

    const int i = tid >> 3;          // output row 0..63
    const int j0 = (tid & 7) << 3;   // first of 8 owned columns

    // adjacency chunk: raw 0/1 floats used as multiplicative mask
    const float4 a0 = *(const float4*)(adj + i * 64 + j0);
    const float4 a1 = *(const float4*)(adj + i * 64 + j0 + 4);

    // stage x[b, n, c, t0..t0+3] -> x_s[t][n][c]  (coalesced float4 loads)
    if (tid < NBANDS * 64) {
        const int n = tid >> 6, c = tid & 63;
        float4 xv = *(const float4*)(x + (((size_t)b * NBANDS + n) * 64 + c) * 128 + t0);
        x_s[0][n][c] = xv.x;
        x_s[1][n][c] = xv.y;
        x_s[2][n][c] = xv.z;
        x_s[3][n][c] = xv.w;
    }
    if (tid < T_TILE * NBANDS) {     // 20 consecutive floats
        const size_t base = ((size_t)b * 128 + t0) * NBANDS;
        const int t = tid / NBANDS, n = tid % NBANDS;
        float mk = amask[base + tid];
        mask_s[t][n] = mk;
        w_s[t][n] = alpha[base + tid] * mk;
    }
    __syncthreads();

    // per-(t,band) sum/min/max over 64 electrodes; 20 pairs over 8 waves
    {
        const int wv = tid >> 6, lane = tid & 63;
        for (int pair = wv; pair < T_TILE * NBANDS; pair += 8) {
            const int t = pair & 3, n = pair >> 2;
            float v = x_s[t][n][lane];
            float sm = v, mx = v, mn = v;
            #pragma unroll
            for (int mk = 32; mk >= 1; mk >>= 1) {
                sm += __shfl_xor(sm, mk);
                mx = fmaxf(mx, __shfl_xor(mx, mk));
                mn = fminf(mn, __shfl_xor(mn, mk));
            }
            if (lane == 0) {
                xbar_s[t][n] = sm * (1.f / 64.f);
                xmax_s[t][n] = mx;
                xmin_s[t][n] = mn;
            }
        }
    }
    __syncthreads();

    // embeddings_mean for 4 t's (threads 0..255: t = tid>>6, d = tid&63)
    if (tid < T_TILE * 64) {
        const int t = tid >> 6, d = tid & 63;
        float cnt = 0.f, accm = 0.f;
        #pragma unroll
        for (int n = 0; n < NBANDS; ++n) {
            cnt += mask_s[t][n];
            accm += mask_s[t][n] * fmaf(xbar_s[t][n], We[n * 64 + d], be[n * 64 + d]);
        }
        out[PFUNC_ELEMS + (size_t)(bt0 + t) * 64 + d] = accm / fmaxf(cnt, 1.f);
    }

    const float maskf[8] = {a0.x, a0.y, a0.z, a0.w, a1.x, a1.y, a1.z, a1.w};

    for (int t = 0; t < T_TILE; ++t) {
        float acc[8];
        #pragma unroll
        for (int jj = 0; jj < 8; ++jj) acc[jj] = 0.f;

        #pragma unroll
        for (int n = 0; n < NBANDS; ++n) {
            // base-2 logits coefficient (0.25*log2e folded into ws)
            const float g2 = fmaf(ws[n], x_s[t][n][i], ws[8 + n]);
            // conservative row bound >= all logits -> exp2 args <= 0, no overflow;
            // self-loop keeps Z >= exp2(-|g2|*range) >> f32 denormal floor
            const float m = (g2 >= 0.f) ? g2 * xmax_s[t][n] : g2 * xmin_s[t][n];
            const float4 xv0 = ((const float4*)(&x_s[t][n][j0]))[0];
            const float4 xv1 = ((const float4*)(&x_s[t][n][j0]))[1];
            float p[8];
            p[0] = __builtin_amdgcn_exp2f(fmaf(g2, xv0.x, -m)) * maskf[0];
            p[1] = __builtin_amdgcn_exp2f(fmaf(g2, xv0.y, -m)) * maskf[1];
            p[2] = __builtin_amdgcn_exp2f(fmaf(g2, xv0.z, -m)) * maskf[2];
            p[3] = __builtin_amdgcn_exp2f(fmaf(g2, xv0.w, -m)) * maskf[3];
            p[4] = __builtin_amdgcn_exp2f(fmaf(g2, xv1.x, -m)) * maskf[4];
            p[5] = __builtin_amdgcn_exp2f(fmaf(g2, xv1.y, -m)) * maskf[5];
            p[6] = __builtin_amdgcn_exp2f(fmaf(g2, xv1.z, -m)) * maskf[6];
            p[7] = __builtin_amdgcn_exp2f(fmaf(g2, xv1.w, -m)) * maskf[7];
            float Z = ((p[0] + p[1]) + (p[2] + p[3])) + ((p[4] + p[5]) + (p[6] + p[7]));
            Z += __shfl_xor(Z, 1);
            Z += __shfl_xor(Z, 2);
            Z += __shfl_xor(Z, 4);
            const float sc = w_s[t][n] * __builtin_amdgcn_rcpf(fmaxf(Z, 1e-30f));
            #pragma unroll
            for (int jj = 0; jj < 8; ++jj) acc[jj] = fmaf(p[jj], sc, acc[jj]);
        }

        float4* outp = (float4*)(out + ((size_t)(bt0 + t) * 64 + i) * 64 + j0);
        outp[0] = make_float4(acc[0], acc[1], acc[2], acc[3]);
        outp[1] = make_float4(acc[4], acc[5], acc[6], acc[7]);
    }
}

extern "C" void kernel_launch(void* const* d_in, const int* in_sizes, int n_in,
                              void* d_out, int out_size, void* d_ws, size_t ws_size,
                              hipStream_t stream) {
    const float* x     = (const float*)d_in[0];
    const float* adj   = (const float*)d_in[1];
    const float* amask = (const float*)d_in[2];
    const float* alpha = (const float*)d_in[3];
    const float* We    = (const float*)d_in[4];
    const float* be    = (const float*)d_in[5];
    const float* Wq    = (const float*)d_in[6];
    const float* Wk    = (const float*)d_in[7];
    float* ws  = (float*)d_ws;
    float* out = (float*)d_out;

    bfp_prep_kernel<<<1, 320, 0, stream>>>(We, be, Wq, Wk, ws);
    bfp_main_kernel<<<1024, 512, 0, stream>>>(x, adj, amask, alpha, We, be, ws, out);
}

// Round 6
// 33.816 us; speedup vs baseline: 1.9410x; 1.0148x over previous
//
#include <hip/hip_runtime.h>
#include <math.h>

#define NBANDS 5
#define T_TILE 4
#define PFUNC_ELEMS (32*128*64*64)
#define LOG2E 1.4426950408889634f

// DPP-based segmented sum over each aligned 8-lane group (VALU pipe, no DS):
//   0xB1 = quad_perm[1,0,3,2] (xor 1), 0x4E = quad_perm[2,3,0,1] (xor 2),
//   0x141 = row_half_mirror (pairs lanes l <-> 7-l within each 8-lane half-row)
#define DPP_ADD(x, ctrl) \
    ((x) + __int_as_float(__builtin_amdgcn_update_dpp(0, __float_as_int(x), (ctrl), 0xF, 0xF, true)))

// ws layout (floats): [0,5) acw = 0.25*log2e*AC[n] ; [8,13) bcw = 0.25*log2e*BC[n]

__global__ void bfp_prep_kernel(const float* __restrict__ We,
                                const float* __restrict__ be,
                                const float* __restrict__ Wq,
                                const float* __restrict__ Wk,
                                float* __restrict__ ws) {
    // 320 threads: wave n = tid>>6 handles band n; lane: s = lane>>2, d-chunk q = lane&3
    const int n = threadIdx.x >> 6;
    const int lane = threadIdx.x & 63;
    const int s = lane >> 2;
    const int d0 = (lane & 3) * 16;
    if (n >= NBANDS) return;

    float u = 0.f, v = 0.f, w = 0.f;
    #pragma unroll
    for (int dd = 0; dd < 16; ++dd) {
        int d = d0 + dd;
        float we = We[n * 64 + d], bb = be[n * 64 + d];
        float wq = Wq[s * 64 + d], wk = Wk[s * 64 + d];
        u = fmaf(wq, we, u);   // A_s partial
        v = fmaf(wk, we, v);   // C_s partial
        w = fmaf(wq, bb, w);   // B_s partial
    }
    // complete each s over its 4 d-chunks (quad xor on bits 0-1)
    #pragma unroll
    for (int mk = 1; mk <= 2; mk <<= 1) {
        u += __shfl_xor(u, mk);
        v += __shfl_xor(v, mk);
        w += __shfl_xor(w, mk);
    }
    float ac = u * v, bc = w * v;   // per-s products (all 4 lanes of a quad identical)
    // sum over s: xor on bits 2-5 keeps lane&3 fixed -> orbit hits each s EXACTLY ONCE
    #pragma unroll
    for (int mk = 4; mk <= 32; mk <<= 1) {
        ac += __shfl_xor(ac, mk);
        bc += __shfl_xor(bc, mk);
    }
    if (lane == 0) {
        ws[n]     = 0.25f * LOG2E * ac;   // 0.25 = 1/sqrt(d_s) only
        ws[8 + n] = 0.25f * LOG2E * bc;
    }
}

__global__ __launch_bounds__(512) void bfp_main_kernel(
        const float* __restrict__ x,      // (32,5,64,128)
        const float* __restrict__ adj,    // (64,64), values in {0,1}
        const float* __restrict__ amask,  // (32,128,5)
        const float* __restrict__ alpha,  // (32,128,5)
        const float* __restrict__ We,     // (5,64)
        const float* __restrict__ be,     // (5,64)
        const float* __restrict__ ws,
        float* __restrict__ out) {
    // 1024 blocks; XCD-bijective swizzle (1024 % 8 == 0): contiguous chunk per XCD
    const int bid = blockIdx.x;
    const int blk = (bid & 7) * 128 + (bid >> 3);
    const int bt0 = blk * T_TILE;         // first of 4 consecutive bt
    const int b = bt0 >> 7;
    const int t0 = bt0 & 127;             // multiple of 4
    const int tid = threadIdx.x;

    __shared__ __align__(16) float x_s[T_TILE][NBANDS][64];
    __shared__ float xbar_s[T_TILE][NBANDS], xmax_s[T_TILE][NBANDS], xmin_s[T_TILE][NBANDS];
    __shared__ float w_s[T_TILE][NBANDS], mask_s[T_TILE][NBANDS];

    const int i = tid >> 3;          // output row 0..63
    const int j0 = (tid & 7) << 3;   // first of 8 owned columns

    // adjacency chunk: raw 0/1 floats used as multiplicative mask
    const float4 a0 = *(const float4*)(adj + i * 64 + j0);
    const float4 a1 = *(const float4*)(adj + i * 64 + j0 + 4);

    // hoist band scalars into registers (n-loops below are fully unrolled)
    float acw[NBANDS], bcw[NBANDS];
    #pragma unroll
    for (int n = 0; n < NBANDS; ++n) { acw[n] = ws[n]; bcw[n] = ws[8 + n]; }

    // stage x[b, n, c, t0..t0+3] -> x_s[t][n][c]  (coalesced float4 loads)
    if (tid < NBANDS * 64) {
        const int n = tid >> 6, c = tid & 63;
        float4 xv = *(const float4*)(x + (((size_t)b * NBANDS + n) * 64 + c) * 128 + t0);
        x_s[0][n][c] = xv.x;
        x_s[1][n][c] = xv.y;
        x_s[2][n][c] = xv.z;
        x_s[3][n][c] = xv.w;
    }
    if (tid < T_TILE * NBANDS) {     // 20 consecutive floats
        const size_t base = ((size_t)b * 128 + t0) * NBANDS;
        const int t = tid / NBANDS, n = tid % NBANDS;
        float mk = amask[base + tid];
        mask_s[t][n] = mk;
        w_s[t][n] = alpha[base + tid] * mk;
    }
    __syncthreads();

    // per-(t,band) sum/min/max over 64 electrodes; 20 pairs over 8 waves
    {
        const int wv = tid >> 6, lane = tid & 63;
        for (int pair = wv; pair < T_TILE * NBANDS; pair += 8) {
            const int t = pair & 3, n = pair >> 2;
            float v = x_s[t][n][lane];
            float sm = v, mx = v, mn = v;
            #pragma unroll
            for (int mk = 32; mk >= 1; mk >>= 1) {
                sm += __shfl_xor(sm, mk);
                mx = fmaxf(mx, __shfl_xor(mx, mk));
                mn = fminf(mn, __shfl_xor(mn, mk));
            }
            if (lane == 0) {
                xbar_s[t][n] = sm * (1.f / 64.f);
                xmax_s[t][n] = mx;
                xmin_s[t][n] = mn;
            }
        }
    }
    __syncthreads();

    // embeddings_mean for 4 t's (threads 0..255: t = tid>>6, d = tid&63)
    if (tid < T_TILE * 64) {
        const int t = tid >> 6, d = tid & 63;
        float cnt = 0.f, accm = 0.f;
        #pragma unroll
        for (int n = 0; n < NBANDS; ++n) {
            cnt += mask_s[t][n];
            accm += mask_s[t][n] * fmaf(xbar_s[t][n], We[n * 64 + d], be[n * 64 + d]);
        }
        out[PFUNC_ELEMS + (size_t)(bt0 + t) * 64 + d] = accm / fmaxf(cnt, 1.f);
    }

    const float maskf[8] = {a0.x, a0.y, a0.z, a0.w, a1.x, a1.y, a1.z, a1.w};

    for (int t = 0; t < T_TILE; ++t) {
        float acc[8];
        #pragma unroll
        for (int jj = 0; jj < 8; ++jj) acc[jj] = 0.f;

        #pragma unroll
        for (int n = 0; n < NBANDS; ++n) {
            // base-2 logits coefficient (0.25*log2e folded into acw/bcw)
            const float g2 = fmaf(acw[n], x_s[t][n][i], bcw[n]);
            // conservative row bound >= all logits -> exp2 args <= 0, no overflow;
            // self-loop keeps Z >= exp2(-|g2|*range) >> f32 denormal floor
            const float m = (g2 >= 0.f) ? g2 * xmax_s[t][n] : g2 * xmin_s[t][n];
            const float4 xv0 = ((const float4*)(&x_s[t][n][j0]))[0];
            const float4 xv1 = ((const float4*)(&x_s[t][n][j0]))[1];
            float p[8];
            p[0] = __builtin_amdgcn_exp2f(fmaf(g2, xv0.x, -m)) * maskf[0];
            p[1] = __builtin_amdgcn_exp2f(fmaf(g2, xv0.y, -m)) * maskf[1];
            p[2] = __builtin_amdgcn_exp2f(fmaf(g2, xv0.z, -m)) * maskf[2];
            p[3] = __builtin_amdgcn_exp2f(fmaf(g2, xv0.w, -m)) * maskf[3];
            p[4] = __builtin_amdgcn_exp2f(fmaf(g2, xv1.x, -m)) * maskf[4];
            p[5] = __builtin_amdgcn_exp2f(fmaf(g2, xv1.y, -m)) * maskf[5];
            p[6] = __builtin_amdgcn_exp2f(fmaf(g2, xv1.z, -m)) * maskf[6];
            p[7] = __builtin_amdgcn_exp2f(fmaf(g2, xv1.w, -m)) * maskf[7];
            float Z = ((p[0] + p[1]) + (p[2] + p[3])) + ((p[4] + p[5]) + (p[6] + p[7]));
            // 8-lane segmented sum entirely on the VALU pipe (no ds_swizzle latency)
            Z = DPP_ADD(Z, 0xB1);    // + lane^1
            Z = DPP_ADD(Z, 0x4E);    // + lane^2
            Z = DPP_ADD(Z, 0x141);   // + mirrored quad within 8-lane group
            const float sc = w_s[t][n] * __builtin_amdgcn_rcpf(fmaxf(Z, 1e-30f));
            #pragma unroll
            for (int jj = 0; jj < 8; ++jj) acc[jj] = fmaf(p[jj], sc, acc[jj]);
        }

        float4* outp = (float4*)(out + ((size_t)(bt0 + t) * 64 + i) * 64 + j0);
        outp[0] = make_float4(acc[0], acc[1], acc[2], acc[3]);
        outp[1] = make_float4(acc[4], acc[5], acc[6], acc[7]);
    }
}

extern "C" void kernel_launch(void* const* d_in, const int* in_sizes, int n_in,
                              void* d_out, int out_size, void* d_ws, size_t ws_size,
                              hipStream_t stream) {
    const float* x     = (const float*)d_in[0];
    const float* adj   = (const float*)d_in[1];
    const float* amask = (const float*)d_in[2];
    const float* alpha = (const float*)d_in[3];
    const float* We    = (const float*)d_in[4];
    const float* be    = (const float*)d_in[5];
    const float* Wq    = (const float*)d_in[6];
    const float* Wk    = (const float*)d_in[7];
    float* ws  = (float*)d_ws;
    float* out = (float*)d_out;

    bfp_prep_kernel<<<1, 320, 0, stream>>>(We, be, Wq, Wk, ws);
    bfp_main_kernel<<<1024, 512, 0, stream>>>(x, adj, amask, alpha, We, be, ws, out);
}

// Round 7
// 31.428 us; speedup vs baseline: 2.0885x; 1.0760x over previous
//
#include <hip/hip_runtime.h>
#include <math.h>

#define NBANDS 5
#define T_TILE 4
#define PFUNC_ELEMS (32*128*64*64)
#define LOG2E 1.4426950408889634f

// DPP segmented sum over each aligned 8-lane group (VALU pipe, no DS pipe):
//   0xB1 = quad_perm[1,0,3,2] (xor 1), 0x4E = quad_perm[2,3,0,1] (xor 2),
//   0x141 = row_half_mirror (l <-> 7-l within each 8-lane half-row)
#define DPP_ADD(x, ctrl) \
    ((x) + __int_as_float(__builtin_amdgcn_update_dpp(0, __float_as_int(x), (ctrl), 0xF, 0xF, true)))

__global__ __launch_bounds__(512) void bfp_kernel(
        const float* __restrict__ x,      // (32,5,64,128)
        const float* __restrict__ adj,    // (64,64), values in {0,1}
        const float* __restrict__ amask,  // (32,128,5)
        const float* __restrict__ alpha,  // (32,128,5)
        const float* __restrict__ We,     // (5,64)
        const float* __restrict__ be,     // (5,64)
        const float* __restrict__ Wq,     // (16,64)
        const float* __restrict__ Wk,     // (16,64)
        float* __restrict__ out) {
    // 1024 blocks; XCD-bijective swizzle (1024 % 8 == 0)
    const int bid = blockIdx.x;
    const int blk = (bid & 7) * 128 + (bid >> 3);
    const int bt0 = blk * T_TILE;
    const int b = bt0 >> 7;
    const int t0 = bt0 & 127;
    const int tid = threadIdx.x;

    __shared__ __align__(16) float x_s[T_TILE][NBANDS][64];
    __shared__ float xbar_s[T_TILE][NBANDS], xmax_s[T_TILE][NBANDS], xmin_s[T_TILE][NBANDS];
    __shared__ float w_s[T_TILE][NBANDS], mask_s[T_TILE][NBANDS];
    __shared__ float acw_s[NBANDS], bcw_s[NBANDS];

    const int i = tid >> 3;          // output row 0..63
    const int j0 = (tid & 7) << 3;   // first of 8 owned columns

    // adjacency chunk: raw 0/1 floats used as multiplicative mask
    const float4 a0 = *(const float4*)(adj + i * 64 + j0);
    const float4 a1 = *(const float4*)(adj + i * 64 + j0 + 4);

    // issue x staging loads early (waves 0..4)
    float4 xstage;
    if (tid < NBANDS * 64)
        xstage = *(const float4*)(x + ((size_t)b * 320 + tid) * 128 + t0);

    // amask/alpha staging on wave 7 (waves 0-4 run fused prep below)
    if (tid >= 512 - T_TILE * NBANDS) {
        const int idx = tid - (512 - T_TILE * NBANDS);      // 0..19
        const size_t base = ((size_t)b * 128 + t0) * NBANDS;
        const int t = idx / NBANDS, n = idx % NBANDS;
        float mk = amask[base + idx];
        mask_s[t][n] = mk;
        w_s[t][n] = alpha[base + idx] * mk;
    }

    // fused prep: wave w (0..4) computes band w's AC/BC redundantly-free
    // (overlaps the in-flight xstage load; ~48 fma + 14 shuffles per wave)
    {
        const int wvid = tid >> 6;
        const int lane = tid & 63;
        if (wvid < NBANDS) {
            const int n = wvid;
            const int s = lane >> 2;          // d_s index 0..15
            const int d0c = (lane & 3) * 16;  // d-chunk
            float u = 0.f, v = 0.f, w = 0.f;
            #pragma unroll
            for (int dd = 0; dd < 16; ++dd) {
                int d = d0c + dd;
                float we = We[n * 64 + d], bb = be[n * 64 + d];
                float wq = Wq[s * 64 + d], wk = Wk[s * 64 + d];
                u = fmaf(wq, we, u);   // A_s partial
                v = fmaf(wk, we, v);   // C_s partial
                w = fmaf(wq, bb, w);   // B_s partial
            }
            #pragma unroll
            for (int mk = 1; mk <= 2; mk <<= 1) {   // complete quads over d-chunks
                u += __shfl_xor(u, mk);
                v += __shfl_xor(v, mk);
                w += __shfl_xor(w, mk);
            }
            float ac = u * v, bc = w * v;           // A_s*C_s, B_s*C_s
            #pragma unroll
            for (int mk = 4; mk <= 32; mk <<= 1) {  // sum over the 16 s (each once)
                ac += __shfl_xor(ac, mk);
                bc += __shfl_xor(bc, mk);
            }
            if (lane == 0) {
                acw_s[n] = 0.25f * LOG2E * ac;  // 1/sqrt(d_s) * log2e folded
                bcw_s[n] = 0.25f * LOG2E * bc;
            }
        }
    }

    // write staged x to LDS: x_s[t][n][c]
    if (tid < NBANDS * 64) {
        const int n = tid >> 6, c = tid & 63;
        x_s[0][n][c] = xstage.x;
        x_s[1][n][c] = xstage.y;
        x_s[2][n][c] = xstage.z;
        x_s[3][n][c] = xstage.w;
    }
    __syncthreads();

    // per-(t,band) sum/min/max over 64 electrodes; 20 pairs over 8 waves
    {
        const int wv = tid >> 6, lane = tid & 63;
        for (int pair = wv; pair < T_TILE * NBANDS; pair += 8) {
            const int t = pair & 3, n = pair >> 2;
            float v = x_s[t][n][lane];
            float sm = v, mx = v, mn = v;
            #pragma unroll
            for (int mk = 32; mk >= 1; mk >>= 1) {
                sm += __shfl_xor(sm, mk);
                mx = fmaxf(mx, __shfl_xor(mx, mk));
                mn = fminf(mn, __shfl_xor(mn, mk));
            }
            if (lane == 0) {
                xbar_s[t][n] = sm * (1.f / 64.f);
                xmax_s[t][n] = mx;
                xmin_s[t][n] = mn;
            }
        }
    }
    __syncthreads();

    // embeddings_mean for 4 t's (threads 0..255)
    if (tid < T_TILE * 64) {
        const int t = tid >> 6, d = tid & 63;
        float cnt = 0.f, accm = 0.f;
        #pragma unroll
        for (int n = 0; n < NBANDS; ++n) {
            cnt += mask_s[t][n];
            accm += mask_s[t][n] * fmaf(xbar_s[t][n], We[n * 64 + d], be[n * 64 + d]);
        }
        out[PFUNC_ELEMS + (size_t)(bt0 + t) * 64 + d] = accm / fmaxf(cnt, 1.f);
    }

    const float maskf[8] = {a0.x, a0.y, a0.z, a0.w, a1.x, a1.y, a1.z, a1.w};

    for (int t = 0; t < T_TILE; ++t) {
        // burst-hoist the per-(t,n) scalar head chains: all 5 bands up front
        float g2v[NBANDS], nmv[NBANDS], wvv[NBANDS];
        #pragma unroll
        for (int n = 0; n < NBANDS; ++n) {
            const float xi = x_s[t][n][i];
            const float g = fmaf(acw_s[n], xi, bcw_s[n]);
            g2v[n] = g;
            // m = max over row of g*x_j bound: branchless, exact same value
            nmv[n] = -fmaxf(g * xmax_s[t][n], g * xmin_s[t][n]);
            wvv[n] = w_s[t][n];
        }

        float acc[8];
        #pragma unroll
        for (int jj = 0; jj < 8; ++jj) acc[jj] = 0.f;

        #pragma unroll
        for (int n = 0; n < NBANDS; ++n) {
            const float g2 = g2v[n], negm = nmv[n];
            const float4 xv0 = ((const float4*)(&x_s[t][n][j0]))[0];
            const float4 xv1 = ((const float4*)(&x_s[t][n][j0]))[1];
            float p[8];
            p[0] = __builtin_amdgcn_exp2f(fmaf(g2, xv0.x, negm)) * maskf[0];
            p[1] = __builtin_amdgcn_exp2f(fmaf(g2, xv0.y, negm)) * maskf[1];
            p[2] = __builtin_amdgcn_exp2f(fmaf(g2, xv0.z, negm)) * maskf[2];
            p[3] = __builtin_amdgcn_exp2f(fmaf(g2, xv0.w, negm)) * maskf[3];
            p[4] = __builtin_amdgcn_exp2f(fmaf(g2, xv1.x, negm)) * maskf[4];
            p[5] = __builtin_amdgcn_exp2f(fmaf(g2, xv1.y, negm)) * maskf[5];
            p[6] = __builtin_amdgcn_exp2f(fmaf(g2, xv1.z, negm)) * maskf[6];
            p[7] = __builtin_amdgcn_exp2f(fmaf(g2, xv1.w, negm)) * maskf[7];
            float Z = ((p[0] + p[1]) + (p[2] + p[3])) + ((p[4] + p[5]) + (p[6] + p[7]));
            Z = DPP_ADD(Z, 0xB1);    // + lane^1
            Z = DPP_ADD(Z, 0x4E);    // + lane^2
            Z = DPP_ADD(Z, 0x141);   // + mirrored quad (8-lane group total)
            const float sc = wvv[n] * __builtin_amdgcn_rcpf(fmaxf(Z, 1e-30f));
            #pragma unroll
            for (int jj = 0; jj < 8; ++jj) acc[jj] = fmaf(p[jj], sc, acc[jj]);
        }

        float4* outp = (float4*)(out + ((size_t)(bt0 + t) * 64 + i) * 64 + j0);
        outp[0] = make_float4(acc[0], acc[1], acc[2], acc[3]);
        outp[1] = make_float4(acc[4], acc[5], acc[6], acc[7]);
    }
}

extern "C" void kernel_launch(void* const* d_in, const int* in_sizes, int n_in,
                              void* d_out, int out_size, void* d_ws, size_t ws_size,
                              hipStream_t stream) {
    const float* x     = (const float*)d_in[0];
    const float* adj   = (const float*)d_in[1];
    const float* amask = (const float*)d_in[2];
    const float* alpha = (const float*)d_in[3];
    const float* We    = (const float*)d_in[4];
    const float* be    = (const float*)d_in[5];
    const float* Wq    = (const float*)d_in[6];
    const float* Wk    = (const float*)d_in[7];
    float* out = (float*)d_out;

    bfp_kernel<<<1024, 512, 0, stream>>>(x, adj, amask, alpha, We, be, Wq, Wk, out);
}